// Round 1
// baseline (168.973 us; speedup 1.0000x reference)
//
#include <hip/hip_runtime.h>
#include <math.h>

#define B_GRAPHS 4096
#define NPG 64
#define E_DIM 128
#define GPG 16   // graphs per block in kernel 2

// ---------------------------------------------------------------------------
// Kernel 1: gather embedding rows + segment max (64 nodes per graph, fixed
// layout since x_batch = repeat(arange(B), 64)).
// grid = (B_GRAPHS, 2 sides), block = 256.
// Each thread: float4 lane q (0..31) of node-group n0 (0..7); loops 8 nodes.
// ---------------------------------------------------------------------------
__global__ __launch_bounds__(256) void gather_max_k(
    const int* __restrict__ lx, const int* __restrict__ rx,
    const float* __restrict__ emb, float* __restrict__ pooled)
{
    const int g    = blockIdx.x;
    const int side = blockIdx.y;
    const int* __restrict__ x = side ? rx : lx;
    const int t = threadIdx.x;

    __shared__ int idx[NPG];
    if (t < NPG) idx[t] = x[g * NPG + t];
    __syncthreads();

    const int n0 = t >> 5;   // node group 0..7
    const int q  = t & 31;   // float4 slot within row (128 f32 = 32 float4)

    float4 acc = make_float4(-INFINITY, -INFINITY, -INFINITY, -INFINITY);
    #pragma unroll
    for (int i = 0; i < 8; ++i) {
        const int n = (i << 3) + n0;
        const float4* __restrict__ row =
            reinterpret_cast<const float4*>(emb + (size_t)idx[n] * E_DIM);
        const float4 v = row[q];
        acc.x = fmaxf(acc.x, v.x);
        acc.y = fmaxf(acc.y, v.y);
        acc.z = fmaxf(acc.z, v.z);
        acc.w = fmaxf(acc.w, v.w);
    }

    __shared__ float4 red[256];
    red[t] = acc;
    __syncthreads();
    if (t < 32) {
        float4 m = red[t];
        #pragma unroll
        for (int j = 1; j < 8; ++j) {
            const float4 v = red[j * 32 + t];
            m.x = fmaxf(m.x, v.x);
            m.y = fmaxf(m.y, v.y);
            m.z = fmaxf(m.z, v.z);
            m.w = fmaxf(m.w, v.w);
        }
        float4* __restrict__ dst = reinterpret_cast<float4*>(
            pooled + ((size_t)side * B_GRAPHS + g) * E_DIM);
        dst[t] = m;
    }
}

// ---------------------------------------------------------------------------
// Kernel 2: per graph, final = pooled @ W^T + b for both sides, then
// cos = dot/(max(|l|,eps)*max(|r|,eps)), hinge-style loss partial sums.
// grid = B_GRAPHS/GPG blocks, block = 256 (threads 0-127: left e, 128-255:
// right e). W staged in LDS with +1 pad -> bank (e+f)%32 (conflict-free).
// ---------------------------------------------------------------------------
__global__ __launch_bounds__(256) void matvec_cos_k(
    const float* __restrict__ pooled, const float* __restrict__ W,
    const float* __restrict__ bias, const float* __restrict__ label,
    float* __restrict__ cos_out, float* __restrict__ partial)
{
    __shared__ float Wl[E_DIM * (E_DIM + 1)];
    __shared__ float P[2][E_DIM];
    __shared__ float F[2][E_DIM];

    const int t = threadIdx.x;
    for (int i = t; i < E_DIM * E_DIM; i += 256)
        Wl[(i >> 7) * (E_DIM + 1) + (i & 127)] = W[i];

    const int side = t >> 7;
    const int e    = t & 127;
    const float be = bias[e];
    float lossAcc = 0.0f;
    __syncthreads();

    for (int gi = 0; gi < GPG; ++gi) {
        const int g = blockIdx.x * GPG + gi;
        P[side][e] = pooled[((size_t)side * B_GRAPHS + g) * E_DIM + e];
        __syncthreads();

        float acc = be;
        const float* __restrict__ wr = &Wl[e * (E_DIM + 1)];
        const float* __restrict__ pv = P[side];
        #pragma unroll 8
        for (int f = 0; f < E_DIM; ++f)
            acc = fmaf(pv[f], wr[f], acc);
        F[side][e] = acc;
        __syncthreads();

        if (t < 64) {
            const float l0 = F[0][t], l1 = F[0][t + 64];
            const float r0 = F[1][t], r1 = F[1][t + 64];
            float dot = l0 * r0 + l1 * r1;
            float nl  = l0 * l0 + l1 * l1;
            float nr  = r0 * r0 + r1 * r1;
            #pragma unroll
            for (int off = 32; off; off >>= 1) {
                dot += __shfl_down(dot, off, 64);
                nl  += __shfl_down(nl,  off, 64);
                nr  += __shfl_down(nr,  off, 64);
            }
            if (t == 0) {
                const float nlv = fmaxf(sqrtf(nl), 1e-6f);
                const float nrv = fmaxf(sqrtf(nr), 1e-6f);
                const float c   = dot / (nlv * nrv);
                cos_out[g] = c;
                const float lab = label[g];
                const float mm  = fmaxf(1.0f - c, 0.0f);
                lossAcc += 0.5f * ((1.0f - lab) * c * c + lab * mm * mm);
            }
        }
        __syncthreads();
    }
    if (t == 0) partial[blockIdx.x] = lossAcc;
}

// ---------------------------------------------------------------------------
// Kernel 3: reduce per-block partial losses -> mean.
// ---------------------------------------------------------------------------
__global__ void loss_reduce_k(const float* __restrict__ partial,
                              float* __restrict__ out, int n)
{
    const int t = threadIdx.x;  // 64 threads
    float s = 0.0f;
    for (int i = t; i < n; i += 64) s += partial[i];
    #pragma unroll
    for (int off = 32; off; off >>= 1) s += __shfl_down(s, off, 64);
    if (t == 0) out[0] = s * (1.0f / (float)B_GRAPHS);
}

// ---------------------------------------------------------------------------
// Inputs (setup_inputs order):
// 0 left_x (N int32), 1 left_graph_index (B), 2 right_x (N), 3 right_graph_index,
// 4 left_x_batch (N), 5 right_x_batch (N), 6 label (B f32),
// 7 emb_table (V*E f32), 8 W (E*E f32), 9 b (E f32)
// Output: [0] = sim_loss, [1..B] = cos  (float32, out_size = B+1)
// ---------------------------------------------------------------------------
extern "C" void kernel_launch(void* const* d_in, const int* in_sizes, int n_in,
                              void* d_out, int out_size, void* d_ws, size_t ws_size,
                              hipStream_t stream)
{
    const int*   lx    = (const int*)d_in[0];
    const int*   rx    = (const int*)d_in[2];
    const float* label = (const float*)d_in[6];
    const float* emb   = (const float*)d_in[7];
    const float* W     = (const float*)d_in[8];
    const float* bias  = (const float*)d_in[9];

    float* out     = (float*)d_out;        // [0]=loss, [1..B]=cos
    float* pooled  = (float*)d_ws;         // 2*B*E floats = 4 MB
    float* partial = pooled + (size_t)2 * B_GRAPHS * E_DIM;  // B/GPG floats

    dim3 g1(B_GRAPHS, 2);
    gather_max_k<<<g1, 256, 0, stream>>>(lx, rx, emb, pooled);

    matvec_cos_k<<<B_GRAPHS / GPG, 256, 0, stream>>>(
        pooled, W, bias, label, out + 1, partial);

    loss_reduce_k<<<1, 64, 0, stream>>>(partial, out, B_GRAPHS / GPG);
}

// Round 3
// 160.624 us; speedup vs baseline: 1.0520x; 1.0520x over previous
//
#include <hip/hip_runtime.h>
#include <math.h>

#define B_GRAPHS 4096
#define NPG 64
#define E_DIM 128
#define INV_B (1.0f / 4096.0f)

// ---------------------------------------------------------------------------
// Single fused kernel. One block per graph (4096 blocks, 256 threads).
//  Phase 1: gather 64+64 embedding rows (left/right), running float4 max.
//  Phase 2: LDS tree reduce -> pooled[2][128] (as float4[2][32]).
//  Phase 3: matvec  final[side][e] = dot(pooled[side], W[e,:]) + b[e]
//           (thread = (side = t&1, e = t>>1); lane pairs share a W row,
//            W streams through L1/L2 - 16KB unique per wave, L1-resident).
//  Phase 4: wave-0 shuffle reduce -> dot, |l|, |r| -> cos -> out[1+g],
//           atomicAdd(out[0], loss/B).
// ---------------------------------------------------------------------------
__global__ __launch_bounds__(256) void fused_graph_sim_k(
    const int* __restrict__ lx, const int* __restrict__ rx,
    const float* __restrict__ emb, const float* __restrict__ W,
    const float* __restrict__ bias, const float* __restrict__ label,
    float* __restrict__ out)
{
    const int g = blockIdx.x;
    const int t = threadIdx.x;

    __shared__ int   idxL[NPG], idxR[NPG];
    __shared__ float4 redL[256], redR[256];
    __shared__ float4 P4[2][32];     // pooled (float4 view of [2][128])
    __shared__ float  F[2][E_DIM];   // finals

    // ---- load node indices for both sides ----
    if (t < NPG)            idxL[t]        = lx[g * NPG + t];
    else if (t < 2 * NPG)   idxR[t - NPG]  = rx[g * NPG + (t - NPG)];
    __syncthreads();

    // ---- phase 1: gather + running max (8 left + 8 right rows / thread) ----
    const int n0 = t >> 5;   // node subgroup 0..7
    const int q  = t & 31;   // float4 slot within a 128-float row
    float4 aL = make_float4(-INFINITY, -INFINITY, -INFINITY, -INFINITY);
    float4 aR = aL;
    #pragma unroll
    for (int i = 0; i < 8; ++i) {
        const int n = (i << 3) + n0;
        const float4 vL =
            reinterpret_cast<const float4*>(emb + (size_t)idxL[n] * E_DIM)[q];
        const float4 vR =
            reinterpret_cast<const float4*>(emb + (size_t)idxR[n] * E_DIM)[q];
        aL.x = fmaxf(aL.x, vL.x); aL.y = fmaxf(aL.y, vL.y);
        aL.z = fmaxf(aL.z, vL.z); aL.w = fmaxf(aL.w, vL.w);
        aR.x = fmaxf(aR.x, vR.x); aR.y = fmaxf(aR.y, vR.y);
        aR.z = fmaxf(aR.z, vR.z); aR.w = fmaxf(aR.w, vR.w);
    }
    redL[t] = aL;
    redR[t] = aR;
    __syncthreads();

    // ---- phase 2: reduce 8 partials per slot (threads 0-31: L, 32-63: R) ----
    if (t < 64) {
        const int side = t >> 5;
        const int qq   = t & 31;
        const float4* __restrict__ src = side ? redR : redL;
        float4 m = src[qq];
        #pragma unroll
        for (int j = 1; j < 8; ++j) {
            const float4 v = src[j * 32 + qq];
            m.x = fmaxf(m.x, v.x); m.y = fmaxf(m.y, v.y);
            m.z = fmaxf(m.z, v.z); m.w = fmaxf(m.w, v.w);
        }
        P4[side][qq] = m;
    }
    __syncthreads();

    // ---- phase 3: matvec. thread -> (side = t&1, e = t>>1) ----
    {
        const int side = t & 1;
        const int e    = t >> 1;
        float acc = bias[e];
        const float4* __restrict__ wr =
            reinterpret_cast<const float4*>(W + (size_t)e * E_DIM);
        const float4* __restrict__ pv = P4[side];
        #pragma unroll 8
        for (int fi = 0; fi < 32; ++fi) {
            const float4 wv = wr[fi];
            const float4 p  = pv[fi];
            acc = fmaf(p.x, wv.x, acc);
            acc = fmaf(p.y, wv.y, acc);
            acc = fmaf(p.z, wv.z, acc);
            acc = fmaf(p.w, wv.w, acc);
        }
        F[side][e] = acc;
    }
    __syncthreads();

    // ---- phase 4: cos + loss (wave 0) ----
    if (t < 64) {
        const float l0 = F[0][t], l1 = F[0][t + 64];
        const float r0 = F[1][t], r1 = F[1][t + 64];
        float dot = l0 * r0 + l1 * r1;
        float nl  = l0 * l0 + l1 * l1;
        float nr  = r0 * r0 + r1 * r1;
        #pragma unroll
        for (int off = 32; off; off >>= 1) {
            dot += __shfl_down(dot, off);
            nl  += __shfl_down(nl,  off);
            nr  += __shfl_down(nr,  off);
        }
        if (t == 0) {
            const float nlv = fmaxf(sqrtf(nl), 1e-6f);
            const float nrv = fmaxf(sqrtf(nr), 1e-6f);
            const float c   = dot / (nlv * nrv);
            out[1 + g] = c;
            const float lab = label[g];
            const float mm  = fmaxf(1.0f - c, 0.0f);
            const float loss = 0.5f * ((1.0f - lab) * c * c + lab * mm * mm);
            atomicAdd(out, loss * INV_B);
        }
    }
}

// ---------------------------------------------------------------------------
// Inputs (setup_inputs order):
// 0 left_x (N int32), 1 left_graph_index (B), 2 right_x (N), 3 right_graph_index,
// 4 left_x_batch (N), 5 right_x_batch (N), 6 label (B f32),
// 7 emb_table (V*E f32), 8 W (E*E f32), 9 b (E f32)
// Output: [0] = sim_loss, [1..B] = cos  (float32, out_size = B+1)
// ---------------------------------------------------------------------------
extern "C" void kernel_launch(void* const* d_in, const int* in_sizes, int n_in,
                              void* d_out, int out_size, void* d_ws, size_t ws_size,
                              hipStream_t stream)
{
    const int*   lx    = (const int*)d_in[0];
    const int*   rx    = (const int*)d_in[2];
    const float* label = (const float*)d_in[6];
    const float* emb   = (const float*)d_in[7];
    const float* W     = (const float*)d_in[8];
    const float* bias  = (const float*)d_in[9];

    float* out = (float*)d_out;   // [0]=loss (atomic-accumulated), [1..B]=cos

    // zero the loss accumulator (graph-capture-safe async memset)
    hipMemsetAsync(out, 0, sizeof(float), stream);

    fused_graph_sim_k<<<B_GRAPHS, 256, 0, stream>>>(
        lx, rx, emb, W, bias, label, out);
}